// Round 1
// baseline (130.223 us; speedup 1.0000x reference)
//
#include <hip/hip_runtime.h>
#include <math.h>

#define NE 64
#define ND 512
#define NH 1024
#define NT 256

#define HCHUNK 64   // H rows per fc1 block -> grid 64*16 = 1024
#define DCHUNK 32   // D rows per fc2 block -> grid 64*16 = 1024
#define TCHA 16     // tokens staged in LDS per fc1 pass (32KB)
#define TCHB 8      // tokens staged in LDS per fc2 pass (32KB)

// ws layout: cnt[NE] ints | tok[NE*NT] ints | h[NT*NH] floats
#define TOK_OFF   (NE)                    // in ints
#define H_OFF_B   (((NE + NE*NT) * 4 + 255) & ~255)  // byte offset, 256B aligned

__global__ void group_kernel(const int* __restrict__ idx,
                             int* __restrict__ cnt, int* __restrict__ tok) {
    int t = threadIdx.x;
    if (t < NE) cnt[t] = 0;
    __syncthreads();
    if (t < NT) {
        int e = idx[t];
        int pos = atomicAdd(&cnt[e], 1);
        tok[e * NT + pos] = t;
    }
}

__global__ __launch_bounds__(256) void fc1_kernel(
    const float* __restrict__ x, const float* __restrict__ w1,
    const int* __restrict__ cnt, const int* __restrict__ tok,
    float* __restrict__ h) {
    __shared__ float xs[TCHA * ND];  // 32 KB

    const int chunks = NH / HCHUNK;
    const int e  = blockIdx.x / chunks;
    const int ch = blockIdx.x % chunks;
    const int nt = cnt[e];
    if (nt == 0) return;

    const int tid  = threadIdx.x;
    const int wave = tid >> 6;
    const int lane = tid & 63;
    const float* w1e = w1 + (size_t)e * NH * ND;
    const int j0 = ch * HCHUNK;
    const int* mytok = tok + e * NT;

    for (int base = 0; base < nt; base += TCHA) {
        const int nc = min(TCHA, nt - base);
        __syncthreads();  // protect xs from previous pass readers
        // stage x rows for this token chunk: nc*128 float4
        for (int i = tid; i < nc * (ND / 4); i += 256) {
            int tt = i >> 7;             // ND/4 = 128
            int kk = (i & 127) * 4;
            *(float4*)(xs + tt * ND + kk) =
                *(const float4*)(x + (size_t)mytok[base + tt] * ND + kk);
        }
        __syncthreads();

        // each wave owns 16 consecutive rows of this 64-row chunk
        for (int r = 0; r < HCHUNK / 4; ++r) {
            const int j = j0 + wave * (HCHUNK / 4) + r;
            const float* wr = w1e + (size_t)j * ND;
            // lane owns k in [4l,4l+4) and [256+4l, 256+4l+4): all 32 banks hit
            const float4 wa = *(const float4*)(wr + lane * 4);
            const float4 wb = *(const float4*)(wr + 256 + lane * 4);
            for (int t = 0; t < nc; ++t) {
                const float* xr = xs + t * ND;
                const float4 xa = *(const float4*)(xr + lane * 4);
                const float4 xb = *(const float4*)(xr + 256 + lane * 4);
                float p = wa.x * xa.x + wa.y * xa.y + wa.z * xa.z + wa.w * xa.w
                        + wb.x * xb.x + wb.y * xb.y + wb.z * xb.z + wb.w * xb.w;
                #pragma unroll
                for (int off = 32; off > 0; off >>= 1)
                    p += __shfl_xor(p, off, 64);
                if (lane == t) {
                    float s = p / (1.0f + __expf(-p));  // silu
                    h[(size_t)mytok[base + t] * NH + j] = s;
                }
            }
        }
    }
}

__global__ __launch_bounds__(256) void fc2_kernel(
    const float* __restrict__ h, const float* __restrict__ w2,
    const int* __restrict__ cnt, const int* __restrict__ tok,
    float* __restrict__ out) {
    __shared__ float hs[TCHB * NH];  // 32 KB

    const int chunks = ND / DCHUNK;
    const int e  = blockIdx.x / chunks;
    const int ch = blockIdx.x % chunks;
    const int nt = cnt[e];
    if (nt == 0) return;

    const int tid  = threadIdx.x;
    const int wave = tid >> 6;
    const int lane = tid & 63;
    const float* w2e = w2 + (size_t)e * ND * NH;
    const int d0 = ch * DCHUNK;
    const int* mytok = tok + e * NT;

    for (int base = 0; base < nt; base += TCHB) {
        const int nc = min(TCHB, nt - base);
        __syncthreads();
        for (int i = tid; i < nc * (NH / 4); i += 256) {
            int tt = i >> 8;             // NH/4 = 256
            int kk = (i & 255) * 4;
            *(float4*)(hs + tt * NH + kk) =
                *(const float4*)(h + (size_t)mytok[base + tt] * NH + kk);
        }
        __syncthreads();

        for (int r = 0; r < DCHUNK / 4; ++r) {
            const int d = d0 + wave * (DCHUNK / 4) + r;
            const float* wr = w2e + (size_t)d * NH;
            const float4 w0 = *(const float4*)(wr + lane * 4);
            const float4 w1v = *(const float4*)(wr + 256 + lane * 4);
            const float4 w2v = *(const float4*)(wr + 512 + lane * 4);
            const float4 w3v = *(const float4*)(wr + 768 + lane * 4);
            for (int t = 0; t < nc; ++t) {
                const float* hr = hs + t * NH;
                const float4 h0 = *(const float4*)(hr + lane * 4);
                const float4 h1 = *(const float4*)(hr + 256 + lane * 4);
                const float4 h2 = *(const float4*)(hr + 512 + lane * 4);
                const float4 h3 = *(const float4*)(hr + 768 + lane * 4);
                float p = w0.x * h0.x + w0.y * h0.y + w0.z * h0.z + w0.w * h0.w
                        + w1v.x * h1.x + w1v.y * h1.y + w1v.z * h1.z + w1v.w * h1.w
                        + w2v.x * h2.x + w2v.y * h2.y + w2v.z * h2.z + w2v.w * h2.w
                        + w3v.x * h3.x + w3v.y * h3.y + w3v.z * h3.z + w3v.w * h3.w;
                #pragma unroll
                for (int off = 32; off > 0; off >>= 1)
                    p += __shfl_xor(p, off, 64);
                if (lane == t)
                    out[(size_t)mytok[base + t] * ND + d] = p;
            }
        }
    }
}

extern "C" void kernel_launch(void* const* d_in, const int* in_sizes, int n_in,
                              void* d_out, int out_size, void* d_ws, size_t ws_size,
                              hipStream_t stream) {
    const float* x    = (const float*)d_in[0];
    const int*   eidx = (const int*)d_in[1];
    const float* fc1w = (const float*)d_in[2];
    const float* fc2w = (const float*)d_in[3];
    float* out = (float*)d_out;

    int*   cnt = (int*)d_ws;
    int*   tok = cnt + TOK_OFF;
    float* h   = (float*)((char*)d_ws + H_OFF_B);

    group_kernel<<<1, 256, 0, stream>>>(eidx, cnt, tok);
    fc1_kernel<<<NE * (NH / HCHUNK), 256, 0, stream>>>(x, fc1w, cnt, tok, h);
    fc2_kernel<<<NE * (ND / DCHUNK), 256, 0, stream>>>(h, fc2w, cnt, tok, out);
}

// Round 2
// 73.738 us; speedup vs baseline: 1.7660x; 1.7660x over previous
//
#include <hip/hip_runtime.h>
#include <math.h>

#define NE 64
#define ND 512
#define NH 1024
#define NT 256
#define NC 8   // compile-time token chunk -> full unroll + ILP

// ws layout: cnt[NE] ints | tok[NE*NT] ints | h[NT*NH] floats
#define TOK_OFF   (NE)
#define H_OFF_B   (((NE + NE*NT) * 4 + 255) & ~255)

__global__ void group_kernel(const int* __restrict__ idx,
                             int* __restrict__ cnt, int* __restrict__ tok) {
    int t = threadIdx.x;
    if (t < NE) cnt[t] = 0;
    __syncthreads();
    if (t < NT) {
        int e = idx[t];
        int pos = atomicAdd(&cnt[e], 1);
        tok[e * NT + pos] = t;
    }
}

// Fused butterfly: v[0..7] hold per-lane partials for 8 tokens.
// Each step halves the accumulator count while exchanging halves, so 8
// reductions cost 7 split shuffles + 3 allreduce shuffles (depth 6) instead
// of 8 x 6 dependent chains. On exit lanes 0..7 hold the full sum for token
// t = bitrev3(lane) = ((lane&1)<<2)|(lane&2)|((lane>>2)&1).
__device__ __forceinline__ float fused_reduce8(float v[NC], int lane) {
#pragma unroll
    for (int i = 0; i < 4; ++i) {
        float lo = v[i], hi = v[i + 4];
        float send = (lane & 1) ? lo : hi;
        float recv = __shfl_xor(send, 1);
        v[i] = ((lane & 1) ? hi : lo) + recv;
    }
#pragma unroll
    for (int i = 0; i < 2; ++i) {
        float lo = v[i], hi = v[i + 2];
        float send = (lane & 2) ? lo : hi;
        float recv = __shfl_xor(send, 2);
        v[i] = ((lane & 2) ? hi : lo) + recv;
    }
    {
        float lo = v[0], hi = v[1];
        float send = (lane & 4) ? lo : hi;
        float recv = __shfl_xor(send, 4);
        v[0] = ((lane & 4) ? hi : lo) + recv;
    }
    v[0] += __shfl_xor(v[0], 8);
    v[0] += __shfl_xor(v[0], 16);
    v[0] += __shfl_xor(v[0], 32);
    return v[0];
}

// fc1: grid = NE * 16 blocks; block = 64 H-rows (4 waves x 16 rows).
// Lane covers k in [4l,4l+4) and [256+4l,256+4l+4)  (coalesced 1KB/instr).
__global__ __launch_bounds__(256) void fc1_kernel(
    const float* __restrict__ x, const float* __restrict__ w1,
    const int* __restrict__ cnt, const int* __restrict__ tok,
    float* __restrict__ h) {
    const int e  = blockIdx.x >> 4;
    const int ch = blockIdx.x & 15;
    const int nt = cnt[e];
    if (nt == 0) return;
    const int tid = threadIdx.x, wave = tid >> 6, lane = tid & 63;
    const float* w1e = w1 + (size_t)e * NH * ND;
    const int j0 = ch * 64 + wave * 16;
    const int* mytok = tok + e * NT;

    for (int base = 0; base < nt; base += NC) {
        float4 xa[NC], xb[NC];
#pragma unroll
        for (int t = 0; t < NC; ++t) {
            if (base + t < nt) {
                const float* xr = x + (size_t)mytok[base + t] * ND;
                xa[t] = *(const float4*)(xr + lane * 4);
                xb[t] = *(const float4*)(xr + 256 + lane * 4);
            } else {
                xa[t] = make_float4(0.f, 0.f, 0.f, 0.f);
                xb[t] = make_float4(0.f, 0.f, 0.f, 0.f);
            }
        }
#pragma unroll 4
        for (int r = 0; r < 16; ++r) {
            const float* wr = w1e + (size_t)(j0 + r) * ND;
            const float4 wa = *(const float4*)(wr + lane * 4);
            const float4 wb = *(const float4*)(wr + 256 + lane * 4);
            float acc[NC];
#pragma unroll
            for (int t = 0; t < NC; ++t) {
                acc[t] = wa.x * xa[t].x + wa.y * xa[t].y + wa.z * xa[t].z + wa.w * xa[t].w
                       + wb.x * xb[t].x + wb.y * xb[t].y + wb.z * xb[t].z + wb.w * xb[t].w;
            }
            float p = fused_reduce8(acc, lane);
            if (lane < NC) {
                int t = ((lane & 1) << 2) | (lane & 2) | ((lane >> 2) & 1);
                if (base + t < nt) {
                    int tk = mytok[base + t];   // reload: avoids runtime-indexed reg array
                    float s = p / (1.0f + __expf(-p));
                    h[(size_t)tk * NH + (j0 + r)] = s;
                }
            }
        }
    }
}

// fc2: grid = NE * 16 blocks; block = 32 D-rows (4 waves x 8 rows).
// Lane covers k in {4l..4l+3} + {0,256,512,768} of NH=1024.
__global__ __launch_bounds__(256) void fc2_kernel(
    const float* __restrict__ h, const float* __restrict__ w2,
    const int* __restrict__ cnt, const int* __restrict__ tok,
    float* __restrict__ out) {
    const int e  = blockIdx.x >> 4;
    const int ch = blockIdx.x & 15;
    const int nt = cnt[e];
    if (nt == 0) return;
    const int tid = threadIdx.x, wave = tid >> 6, lane = tid & 63;
    const float* w2e = w2 + (size_t)e * ND * NH;
    const int d0 = ch * 32 + wave * 8;
    const int* mytok = tok + e * NT;

    for (int base = 0; base < nt; base += NC) {
        float4 hb0[NC], hb1[NC], hb2[NC], hb3[NC];
#pragma unroll
        for (int t = 0; t < NC; ++t) {
            if (base + t < nt) {
                const float* hr = h + (size_t)mytok[base + t] * NH;
                hb0[t] = *(const float4*)(hr + lane * 4);
                hb1[t] = *(const float4*)(hr + 256 + lane * 4);
                hb2[t] = *(const float4*)(hr + 512 + lane * 4);
                hb3[t] = *(const float4*)(hr + 768 + lane * 4);
            } else {
                hb0[t] = make_float4(0.f, 0.f, 0.f, 0.f);
                hb1[t] = make_float4(0.f, 0.f, 0.f, 0.f);
                hb2[t] = make_float4(0.f, 0.f, 0.f, 0.f);
                hb3[t] = make_float4(0.f, 0.f, 0.f, 0.f);
            }
        }
#pragma unroll 2
        for (int r = 0; r < 8; ++r) {
            const float* wr = w2e + (size_t)(d0 + r) * NH;
            const float4 w0 = *(const float4*)(wr + lane * 4);
            const float4 w1v = *(const float4*)(wr + 256 + lane * 4);
            const float4 w2v = *(const float4*)(wr + 512 + lane * 4);
            const float4 w3v = *(const float4*)(wr + 768 + lane * 4);
            float acc[NC];
#pragma unroll
            for (int t = 0; t < NC; ++t) {
                acc[t] = w0.x * hb0[t].x + w0.y * hb0[t].y + w0.z * hb0[t].z + w0.w * hb0[t].w
                       + w1v.x * hb1[t].x + w1v.y * hb1[t].y + w1v.z * hb1[t].z + w1v.w * hb1[t].w
                       + w2v.x * hb2[t].x + w2v.y * hb2[t].y + w2v.z * hb2[t].z + w2v.w * hb2[t].w
                       + w3v.x * hb3[t].x + w3v.y * hb3[t].y + w3v.z * hb3[t].z + w3v.w * hb3[t].w;
            }
            float p = fused_reduce8(acc, lane);
            if (lane < NC) {
                int t = ((lane & 1) << 2) | (lane & 2) | ((lane >> 2) & 1);
                if (base + t < nt) {
                    int tk = mytok[base + t];
                    out[(size_t)tk * ND + (d0 + r)] = p;
                }
            }
        }
    }
}

extern "C" void kernel_launch(void* const* d_in, const int* in_sizes, int n_in,
                              void* d_out, int out_size, void* d_ws, size_t ws_size,
                              hipStream_t stream) {
    const float* x    = (const float*)d_in[0];
    const int*   eidx = (const int*)d_in[1];
    const float* fc1w = (const float*)d_in[2];
    const float* fc2w = (const float*)d_in[3];
    float* out = (float*)d_out;

    int*   cnt = (int*)d_ws;
    int*   tok = cnt + TOK_OFF;
    float* h   = (float*)((char*)d_ws + H_OFF_B);

    group_kernel<<<1, 256, 0, stream>>>(eidx, cnt, tok);
    fc1_kernel<<<NE * 16, 256, 0, stream>>>(x, fc1w, cnt, tok, h);
    fc2_kernel<<<NE * 16, 256, 0, stream>>>(h, fc2w, cnt, tok, out);
}

// Round 3
// 70.030 us; speedup vs baseline: 1.8595x; 1.0530x over previous
//
#include <hip/hip_runtime.h>
#include <math.h>

#define NE 64
#define ND 512
#define NH 1024
#define NT 256
#define NC 8   // compile-time token chunk -> full unroll + ILP

// ws layout: h[NT*NH] floats
__device__ __forceinline__ int build_group(const int* __restrict__ idx, int e,
                                           int* tok_lds, int* wsum) {
    const int t = threadIdx.x, wave = t >> 6, lane = t & 63;
    const bool m = (idx[t] == e);
    const unsigned long long mask = __ballot(m);
    if (lane == 0) wsum[wave] = __popcll(mask);
    __syncthreads();
    int before = 0;
#pragma unroll
    for (int w = 0; w < 3; ++w) before += (w < wave) ? wsum[w] : 0;
    const int nt = wsum[0] + wsum[1] + wsum[2] + wsum[3];
    if (m) {
        int pos = before + __popcll(mask & ((1ull << lane) - 1ull));
        tok_lds[pos] = t;
    }
    __syncthreads();
    // pad so fragment loads can be unconditional (dupes of token 0; stores
    // stay guarded by nt so results for pad slots are discarded)
    if (nt > 0 && t >= nt && t < nt + NC) tok_lds[t] = tok_lds[0];
    __syncthreads();
    return nt;
}

// Fused butterfly: v[0..7] hold per-lane partials for 8 tokens. 10 shuffles,
// depth 6, for all 8 reductions. On exit lanes 0..7 hold the sum for token
// t = bitrev3(lane).
__device__ __forceinline__ float fused_reduce8(float v[NC], int lane) {
#pragma unroll
    for (int i = 0; i < 4; ++i) {
        float lo = v[i], hi = v[i + 4];
        float send = (lane & 1) ? lo : hi;
        float recv = __shfl_xor(send, 1);
        v[i] = ((lane & 1) ? hi : lo) + recv;
    }
#pragma unroll
    for (int i = 0; i < 2; ++i) {
        float lo = v[i], hi = v[i + 2];
        float send = (lane & 2) ? lo : hi;
        float recv = __shfl_xor(send, 2);
        v[i] = ((lane & 2) ? hi : lo) + recv;
    }
    {
        float lo = v[0], hi = v[1];
        float send = (lane & 4) ? lo : hi;
        float recv = __shfl_xor(send, 4);
        v[0] = ((lane & 4) ? hi : lo) + recv;
    }
    v[0] += __shfl_xor(v[0], 8);
    v[0] += __shfl_xor(v[0], 16);
    v[0] += __shfl_xor(v[0], 32);
    return v[0];
}

// fc1: grid = NE*16; block owns 64 H-rows (4 waves x 16 rows).
// Lane covers k in [4l,4l+4) and [256+4l,256+4l+4)  (coalesced 1KB/instr).
__global__ __launch_bounds__(256) void fc1_kernel(
    const float* __restrict__ x, const float* __restrict__ w1,
    const int* __restrict__ idx, float* __restrict__ h) {
    __shared__ int tok_lds[NT + NC];
    __shared__ int wsum[4];
    const int e  = blockIdx.x >> 4;
    const int ch = blockIdx.x & 15;
    const int tid = threadIdx.x, wave = tid >> 6, lane = tid & 63;
    const int nt = build_group(idx, e, tok_lds, wsum);
    if (nt == 0) return;
    const float* w1e = w1 + (size_t)e * NH * ND;
    const int j0 = ch * 64 + wave * 16;

    for (int base = 0; base < nt; base += NC) {
        float4 xa[NC], xb[NC];
#pragma unroll
        for (int t = 0; t < NC; ++t) {
            const float* xr = x + (size_t)tok_lds[base + t] * ND;
            xa[t] = *(const float4*)(xr + lane * 4);
            xb[t] = *(const float4*)(xr + 256 + lane * 4);
        }
#pragma unroll 4
        for (int r = 0; r < 16; ++r) {
            const float* wr = w1e + (size_t)(j0 + r) * ND;
            const float4 wa = *(const float4*)(wr + lane * 4);
            const float4 wb = *(const float4*)(wr + 256 + lane * 4);
            float acc[NC];
#pragma unroll
            for (int t = 0; t < NC; ++t) {
                acc[t] = wa.x * xa[t].x + wa.y * xa[t].y + wa.z * xa[t].z + wa.w * xa[t].w
                       + wb.x * xb[t].x + wb.y * xb[t].y + wb.z * xb[t].z + wb.w * xb[t].w;
            }
            float p = fused_reduce8(acc, lane);
            if (lane < NC) {
                int t = ((lane & 1) << 2) | (lane & 2) | ((lane >> 2) & 1);
                if (base + t < nt) {
                    int tk = tok_lds[base + t];
                    float s = p / (1.0f + __expf(-p));
                    h[(size_t)tk * NH + (j0 + r)] = s;
                }
            }
        }
    }
}

// fc2: grid = NE*16; block owns 32 D-rows (4 waves x 8 rows).
// Lane covers k in {4l..4l+3} + {0,256,512,768} of NH=1024.
__global__ __launch_bounds__(256) void fc2_kernel(
    const float* __restrict__ h, const float* __restrict__ w2,
    const int* __restrict__ idx, float* __restrict__ out) {
    __shared__ int tok_lds[NT + NC];
    __shared__ int wsum[4];
    const int e  = blockIdx.x >> 4;
    const int ch = blockIdx.x & 15;
    const int tid = threadIdx.x, wave = tid >> 6, lane = tid & 63;
    const int nt = build_group(idx, e, tok_lds, wsum);
    if (nt == 0) return;
    const float* w2e = w2 + (size_t)e * ND * NH;
    const int d0 = ch * 32 + wave * 8;

    for (int base = 0; base < nt; base += NC) {
        float4 hb0[NC], hb1[NC], hb2[NC], hb3[NC];
#pragma unroll
        for (int t = 0; t < NC; ++t) {
            const float* hr = h + (size_t)tok_lds[base + t] * NH;
            hb0[t] = *(const float4*)(hr + lane * 4);
            hb1[t] = *(const float4*)(hr + 256 + lane * 4);
            hb2[t] = *(const float4*)(hr + 512 + lane * 4);
            hb3[t] = *(const float4*)(hr + 768 + lane * 4);
        }
#pragma unroll 2
        for (int r = 0; r < 8; ++r) {
            const float* wr = w2e + (size_t)(d0 + r) * NH;
            const float4 w0 = *(const float4*)(wr + lane * 4);
            const float4 w1v = *(const float4*)(wr + 256 + lane * 4);
            const float4 w2v = *(const float4*)(wr + 512 + lane * 4);
            const float4 w3v = *(const float4*)(wr + 768 + lane * 4);
            float acc[NC];
#pragma unroll
            for (int t = 0; t < NC; ++t) {
                acc[t] = w0.x * hb0[t].x + w0.y * hb0[t].y + w0.z * hb0[t].z + w0.w * hb0[t].w
                       + w1v.x * hb1[t].x + w1v.y * hb1[t].y + w1v.z * hb1[t].z + w1v.w * hb1[t].w
                       + w2v.x * hb2[t].x + w2v.y * hb2[t].y + w2v.z * hb2[t].z + w2v.w * hb2[t].w
                       + w3v.x * hb3[t].x + w3v.y * hb3[t].y + w3v.z * hb3[t].z + w3v.w * hb3[t].w;
            }
            float p = fused_reduce8(acc, lane);
            if (lane < NC) {
                int t = ((lane & 1) << 2) | (lane & 2) | ((lane >> 2) & 1);
                if (base + t < nt) {
                    int tk = tok_lds[base + t];
                    out[(size_t)tk * ND + (d0 + r)] = p;
                }
            }
        }
    }
}

extern "C" void kernel_launch(void* const* d_in, const int* in_sizes, int n_in,
                              void* d_out, int out_size, void* d_ws, size_t ws_size,
                              hipStream_t stream) {
    const float* x    = (const float*)d_in[0];
    const int*   eidx = (const int*)d_in[1];
    const float* fc1w = (const float*)d_in[2];
    const float* fc2w = (const float*)d_in[3];
    float* out = (float*)d_out;
    float* h   = (float*)d_ws;

    fc1_kernel<<<NE * 16, 256, 0, stream>>>(x, fc1w, eidx, h);
    fc2_kernel<<<NE * 16, 256, 0, stream>>>(h, fc2w, eidx, out);
}